// Round 11
// baseline (86.030 us; speedup 1.0000x reference)
//
#include <hip/hip_runtime.h>

typedef float f32x4 __attribute__((ext_vector_type(4)));

__device__ __forceinline__ float relu_(float v) { return fmaxf(v, 0.f); }
// Intra-wave LDS fence: wave is lockstep; drain our own LDS ops + stop compiler
// reordering across the fence.
__device__ __forceinline__ void wave_sync() {
    asm volatile("s_waitcnt lgkmcnt(0)" ::: "memory");
}

// PAIRS_A = {0,0,4,1,2,2,6,3} ; PAIRS_B = {4,1,5,5,6,3,7,7} packed as nibbles
#define PA_PACK 0x36221400u
#define PB_PACK 0x77365514u

// ---------------- pre-kernel: batch-independent yk[64][20] and c0 ----------
__global__ void yk_kernel(
    const float* __restrict__ mask,
    const float* __restrict__ wm1, const float* __restrict__ bm1,
    const float* __restrict__ wm2, const float* __restrict__ bm2,
    const float* __restrict__ wm3, const float* __restrict__ bm3,
    const float* __restrict__ wk1, const float* __restrict__ bk1,
    const float* __restrict__ wk2, const float* __restrict__ bk2,
    float* __restrict__ ws)   // ws[0..1279] = yk[ij][c]; ws[1280] = c0
{
    int tid = threadIdx.x;
    int ij = tid >> 2, coff = (tid & 3) * 5;
    int i = ij >> 3, j = ij & 7;
    float m = mask[i * 8 + j];
    float a[4];
#pragma unroll
    for (int q = 0; q < 4; q++) a[q] = relu_(fmaf(m, wm1[q], bm1[q]));
    float b2[20];
#pragma unroll
    for (int c = 0; c < 20; c++) {
        float acc = bm2[c];
#pragma unroll
        for (int q = 0; q < 4; q++) acc = fmaf(a[q], wm2[q * 20 + c], acc);
        b2[c] = relu_(acc);
    }
#pragma unroll
    for (int cc = 0; cc < 5; cc++) {
        int c = coff + cc;
        float acc = bm3[c];
#pragma unroll
        for (int k = 0; k < 20; k++) acc = fmaf(b2[k], wm3[k * 20 + c], acc);
        float y = relu_(acc);
        float wkk = 0.f;
#pragma unroll
        for (int q = 0; q < 8; q++) wkk = fmaf(wk1[c * 8 + q], wk2[q], wkk);
        ws[ij * 20 + c] = y * wkk;
    }
    if (tid == 0) {
        float c0 = bk2[0];
#pragma unroll
        for (int q = 0; q < 8; q++) c0 = fmaf(bk1[q], wk2[q], c0);
        ws[1280] = c0;
    }
}

// ---------------- main kernel: 4 batches per wave, 16 lanes per batch.
// lane = (g, jh, i). ALL-SCALAR fp32: every MAC is v_fmac_f32 vdst,s,v with
// the weight folded from an SGPR (wave-uniform s_load). No f32x2 state, no
// inline-asm math — the two patterns that triggered AGPR-split demotion in
// R3/R4/R5/R9/R10. Weight rows accessed contiguously -> s_load_dwordx4/x8.
__global__ __launch_bounds__(256, 6) void frap_kernel(
    const float* __restrict__ x,
    const float* __restrict__ wv1, const float* __restrict__ bv1,
    const float* __restrict__ wv2, const float* __restrict__ bv2,
    const float* __restrict__ wp1, const float* __restrict__ bp1,
    const float* __restrict__ wp2, const float* __restrict__ bp2,
    const float* __restrict__ we,  const float* __restrict__ be,
    const float* __restrict__ wc1, const float* __restrict__ bc1,
    const float* __restrict__ wc2, const float* __restrict__ bc2,
    const float* __restrict__ ykg,
    float* __restrict__ out, int Btot)
{
    // v layout (dwords): voff(w,g,r) = w*656 + g*164 + r*20
    // row stride 20, group stride 164: b128 reads conflict-free (checked).
    __shared__ float s_v[4 * 656];

    const int tid  = threadIdx.x;
    const int w    = tid >> 6;
    const int lane = tid & 63;
    const int g    = lane >> 4;
    const int jh   = (lane >> 3) & 1;
    const int i    = lane & 7;
    const int b    = blockIdx.x * 16 + w * 4 + g;
    const int bb   = (b < Btot) ? b : (Btot - 1);   // clamp loads; guard stores

    const int pa = (PA_PACK >> (4 * i)) & 15;
    const int pb = (PB_PACK >> (4 * i)) & 15;

    // ---- cat rows pa and pb, inline (weights uniform -> s_load) ----
    float ca[8], cb[8];
    {
        const float xva = x[bb * 16 + pa];
        const float xpa = x[bb * 16 + 8 + pa];
        const float xvb = x[bb * 16 + pb];
        const float xpb = x[bb * 16 + 8 + pb];

        float t0 = relu_(fmaf(xva, wv1[0], bv1[0]));
        float t1 = relu_(fmaf(xva, wv1[1], bv1[1]));
#pragma unroll
        for (int q = 0; q < 4; q++)
            ca[q] = relu_(fmaf(t0, wv2[q], fmaf(t1, wv2[4 + q], bv2[q])));
        float p0 = relu_(fmaf(xpa, wp1[0], bp1[0]));
        float p1 = relu_(fmaf(xpa, wp1[1], bp1[1]));
#pragma unroll
        for (int q = 0; q < 4; q++)
            ca[4 + q] = relu_(fmaf(p0, wp2[q], fmaf(p1, wp2[4 + q], bp2[q])));

        float s0 = relu_(fmaf(xvb, wv1[0], bv1[0]));
        float s1 = relu_(fmaf(xvb, wv1[1], bv1[1]));
#pragma unroll
        for (int q = 0; q < 4; q++)
            cb[q] = relu_(fmaf(s0, wv2[q], fmaf(s1, wv2[4 + q], bv2[q])));
        float r0 = relu_(fmaf(xpb, wp1[0], bp1[0]));
        float r1 = relu_(fmaf(xpb, wp1[1], bp1[1]));
#pragma unroll
        for (int q = 0; q < 4; q++)
            cb[4 + q] = relu_(fmaf(r0, wp2[q], fmaf(r1, wp2[4 + q], bp2[q])));
    }

    // ---- pd row i: f-outer / k-inner so we[f][0..15] is a contiguous run ----
    float da[16], db[16];
#pragma unroll
    for (int k = 0; k < 16; k++) { da[k] = be[k]; db[k] = be[k]; }
#pragma unroll
    for (int f = 0; f < 8; f++) {
        const float caf = ca[f], cbf = cb[f];
#pragma unroll
        for (int k = 0; k < 16; k++) {
            const float wf = we[f * 16 + k];          // contiguous -> s_load_dwordx4
            da[k] = fmaf(caf, wf, da[k]);
            db[k] = fmaf(cbf, wf, db[k]);
        }
    }
    float pd[16];
#pragma unroll
    for (int k = 0; k < 16; k++) pd[k] = relu_(da[k]) + relu_(db[k]);

    // ---- u[i] (regs) and v[i] (LDS): k-outer / c-inner (contiguous rows) ----
    float u[20], vv[20];
#pragma unroll
    for (int c = 0; c < 20; c++) { u[c] = bc1[c]; vv[c] = 0.f; }
#pragma unroll
    for (int k = 0; k < 16; k++) {
        const float pk_ = pd[k];
#pragma unroll
        for (int c = 0; c < 20; c++)
            u[c] = fmaf(pk_, wc1[k * 20 + c], u[c]);      // v_fmac v,s,v
    }
#pragma unroll
    for (int k = 0; k < 16; k++) {
        const float pk_ = pd[k];
#pragma unroll
        for (int c = 0; c < 20; c++)
            vv[c] = fmaf(pk_, wc1[(16 + k) * 20 + c], vv[c]);
    }
    const int vbase = w * 656 + g * 164 + i * 20;
    if (jh == 0) {
#pragma unroll
        for (int p = 0; p < 5; p++) {
            f32x4 t; t.x = vv[4*p]; t.y = vv[4*p+1]; t.z = vv[4*p+2]; t.w = vv[4*p+3];
            *(f32x4*)&s_v[vbase + 4 * p] = t;             // 5x ds_write_b128
        }
    }
    wave_sync();   // per-wave LDS region; wave lockstep => visible to all lanes

    // ---- stage 4: lane owns (i, jh); four iterations, one j each ----
    const float c0 = ykg[1280];                           // uniform -> s_load
    const int vg = w * 656 + g * 164;
    const float* __restrict__ ykrow = ykg + i * 160;      // + j*20

#pragma unroll 1
    for (int t = 0; t < 4; t++) {
        const int j = jh * 4 + t;

        float vj[20];
#pragma unroll
        for (int p = 0; p < 5; p++) {
            f32x4 q = *(const f32x4*)&s_v[vg + j * 20 + 4 * p];  // b128, bcast
            vj[4*p] = q.x; vj[4*p+1] = q.y; vj[4*p+2] = q.z; vj[4*p+3] = q.w;
        }

        float s2[20];
#pragma unroll
        for (int c = 0; c < 20; c++) s2[c] = bc2[c];
#pragma unroll
        for (int k = 0; k < 20; k++) {
            const float hk = relu_(u[k] + vj[k]);
#pragma unroll
            for (int c = 0; c < 20; c++)
                s2[c] = fmaf(hk, wc2[k * 20 + c], s2[c]); // v_fmac v,s,v
        }

        // epilogue: z = c0 + sum relu(s2)*yk  (yk row L1-hot, global b128)
        float z = c0;
#pragma unroll
        for (int p = 0; p < 5; p++) {
            f32x4 y4 = *(const f32x4*)&ykrow[j * 20 + 4 * p];
            z = fmaf(relu_(s2[4*p+0]), y4.x, z);
            z = fmaf(relu_(s2[4*p+1]), y4.y, z);
            z = fmaf(relu_(s2[4*p+2]), y4.z, z);
            z = fmaf(relu_(s2[4*p+3]), y4.w, z);
        }
        if (b < Btot)
            out[b * 64 + i * 8 + j] = z;
    }
}

extern "C" void kernel_launch(void* const* d_in, const int* in_sizes, int n_in,
                              void* d_out, int out_size, void* d_ws, size_t ws_size,
                              hipStream_t stream) {
    const float* x    = (const float*)d_in[0];
    const float* mask = (const float*)d_in[1];
    const float* wv1  = (const float*)d_in[2];
    const float* bv1  = (const float*)d_in[3];
    const float* wv2  = (const float*)d_in[4];
    const float* bv2  = (const float*)d_in[5];
    const float* wp1  = (const float*)d_in[6];
    const float* bp1  = (const float*)d_in[7];
    const float* wp2  = (const float*)d_in[8];
    const float* bp2  = (const float*)d_in[9];
    const float* we   = (const float*)d_in[10];
    const float* be   = (const float*)d_in[11];
    const float* wc1  = (const float*)d_in[12];
    const float* bc1  = (const float*)d_in[13];
    const float* wc2  = (const float*)d_in[14];
    const float* bc2  = (const float*)d_in[15];
    const float* wm1  = (const float*)d_in[16];
    const float* bm1  = (const float*)d_in[17];
    const float* wm2  = (const float*)d_in[18];
    const float* bm2  = (const float*)d_in[19];
    const float* wm3  = (const float*)d_in[20];
    const float* bm3  = (const float*)d_in[21];
    const float* wk1  = (const float*)d_in[22];
    const float* bk1  = (const float*)d_in[23];
    const float* wk2  = (const float*)d_in[24];
    const float* bk2  = (const float*)d_in[25];
    float* out = (float*)d_out;
    float* ws  = (float*)d_ws;

    int Btot = in_sizes[0] / 16;                 // 32768

    yk_kernel<<<1, 256, 0, stream>>>(mask, wm1, bm1, wm2, bm2, wm3, bm3,
                                     wk1, bk1, wk2, bk2, ws);

    int grid = (Btot + 15) / 16;                 // 16 batches per 256-thr block
    frap_kernel<<<grid, 256, 0, stream>>>(
        x, wv1, bv1, wv2, bv2, wp1, bp1, wp2, bp2, we, be,
        wc1, bc1, wc2, bc2, ws, out, Btot);
}

// Round 12
// 63.379 us; speedup vs baseline: 1.3574x; 1.3574x over previous
//
#include <hip/hip_runtime.h>

typedef float f32x2 __attribute__((ext_vector_type(2)));
typedef float f32x4 __attribute__((ext_vector_type(4)));

__device__ __forceinline__ float relu_(float v) { return fmaxf(v, 0.f); }
// Intra-wave LDS fence: wave is lockstep; drain our own LDS ops + stop compiler
// reordering across the fence.
__device__ __forceinline__ void wave_sync() {
    asm volatile("s_waitcnt lgkmcnt(0)" ::: "memory");
}
// acc += hv * w   (w folded from SGPR pair; proven clean in R10)
__device__ __forceinline__ void pk_fma_sw(f32x2& acc, f32x2 hv, f32x2 w) {
    asm("v_pk_fma_f32 %0, %1, %2, %0" : "+v"(acc) : "v"(hv), "s"(w));
}

// PAIRS_A = {0,0,4,1,2,2,6,3} ; PAIRS_B = {4,1,5,5,6,3,7,7} packed as nibbles
#define PA_PACK 0x36221400u
#define PB_PACK 0x77365514u

// ---------------- pre-kernel: yk stored as [ij][half][12] (12-padded halves
// so each half is 16B-aligned: 2 b128 + 1 b64 loads). ws[1536] = c0.
__global__ void yk_kernel(
    const float* __restrict__ mask,
    const float* __restrict__ wm1, const float* __restrict__ bm1,
    const float* __restrict__ wm2, const float* __restrict__ bm2,
    const float* __restrict__ wm3, const float* __restrict__ bm3,
    const float* __restrict__ wk1, const float* __restrict__ bk1,
    const float* __restrict__ wk2, const float* __restrict__ bk2,
    float* __restrict__ ws)
{
    int tid = threadIdx.x;
    int ij = tid >> 2, coff = (tid & 3) * 5;
    int i = ij >> 3, j = ij & 7;
    float m = mask[i * 8 + j];
    float a[4];
#pragma unroll
    for (int q = 0; q < 4; q++) a[q] = relu_(fmaf(m, wm1[q], bm1[q]));
    float b2[20];
#pragma unroll
    for (int c = 0; c < 20; c++) {
        float acc = bm2[c];
#pragma unroll
        for (int q = 0; q < 4; q++) acc = fmaf(a[q], wm2[q * 20 + c], acc);
        b2[c] = relu_(acc);
    }
#pragma unroll
    for (int cc = 0; cc < 5; cc++) {
        int c = coff + cc;
        float acc = bm3[c];
#pragma unroll
        for (int k = 0; k < 20; k++) acc = fmaf(b2[k], wm3[k * 20 + c], acc);
        float y = relu_(acc);
        float wkk = 0.f;
#pragma unroll
        for (int q = 0; q < 8; q++) wkk = fmaf(wk1[c * 8 + q], wk2[q], wkk);
        int half = (c >= 10), cc12 = c - 10 * half;
        ws[ij * 24 + half * 12 + cc12] = y * wkk;
    }
    if (tid == 0) {
        float c0 = bk2[0];
#pragma unroll
        for (int q = 0; q < 8; q++) c0 = fmaf(bk1[q], wk2[q], c0);
        ws[1536] = c0;
    }
}

// ---------------- main kernel: 4 batches per wave, 16 lanes per batch.
// lane = (g, jh, i). jh=0 lane computes u row i -> LDS; jh=1 computes v row i
// -> LDS (halves stage-3 work, removes u from registers). Stage 4: lane owns
// (i, jh), 4 j's; per j: h1[20] regs, s2 in TWO 10-col half-passes (5 f32x2
// accs live). Peak live ~45 regs so the DEFAULT 64-VGPR budget holds all
// state in true VGPRs (no launch_bounds: R3/4/5/9/10/11 showed any cap ->
// AGPR split -> 1.5-3.5x VALU inflation).
__global__ void frap_kernel(
    const float* __restrict__ x,
    const float* __restrict__ wv1, const float* __restrict__ bv1,
    const float* __restrict__ wv2, const float* __restrict__ bv2,
    const float* __restrict__ wp1, const float* __restrict__ bp1,
    const float* __restrict__ wp2, const float* __restrict__ bp2,
    const float* __restrict__ we,  const float* __restrict__ be,
    const float* __restrict__ wc1, const float* __restrict__ bc1,
    const float* __restrict__ wc2, const float* __restrict__ bc2,
    const float* __restrict__ ykg,
    float* __restrict__ out, int Btot)
{
    // s_uv dword layout: row r of (w,g) at ((w*4+g)*16 + r)*20, r = jh*8+i
    // (u rows 0-7, v rows 8-15). Row starts mod 32 banks: i*20 -> 8 distinct
    // spans; jh adds 160 (=0 mod 32): 2-way (free); g adds 320 (=0 mod 32):
    // different addresses, same spans -> <=4-way on writes, reads are
    // broadcast-heavy (8 lanes same address for v; 2 for u). 20 KB/block.
    __shared__ float s_uv[16 * 16 * 20];

    const int tid  = threadIdx.x;
    const int w    = tid >> 6;
    const int lane = tid & 63;
    const int g    = lane >> 4;
    const int jh   = (lane >> 3) & 1;
    const int i    = lane & 7;
    const int b    = blockIdx.x * 16 + w * 4 + g;
    const int bb   = (b < Btot) ? b : (Btot - 1);   // clamp loads; guard stores

    const int pa = (PA_PACK >> (4 * i)) & 15;
    const int pb = (PB_PACK >> (4 * i)) & 15;

    // ---- cat rows pa and pb, inline (weights uniform -> s_load) ----
    float ca[8], cb[8];
    {
        const float xva = x[bb * 16 + pa];
        const float xpa = x[bb * 16 + 8 + pa];
        const float xvb = x[bb * 16 + pb];
        const float xpb = x[bb * 16 + 8 + pb];

        float t0 = relu_(fmaf(xva, wv1[0], bv1[0]));
        float t1 = relu_(fmaf(xva, wv1[1], bv1[1]));
#pragma unroll
        for (int q = 0; q < 4; q++)
            ca[q] = relu_(fmaf(t0, wv2[q], fmaf(t1, wv2[4 + q], bv2[q])));
        float p0 = relu_(fmaf(xpa, wp1[0], bp1[0]));
        float p1 = relu_(fmaf(xpa, wp1[1], bp1[1]));
#pragma unroll
        for (int q = 0; q < 4; q++)
            ca[4 + q] = relu_(fmaf(p0, wp2[q], fmaf(p1, wp2[4 + q], bp2[q])));

        float s0 = relu_(fmaf(xvb, wv1[0], bv1[0]));
        float s1 = relu_(fmaf(xvb, wv1[1], bv1[1]));
#pragma unroll
        for (int q = 0; q < 4; q++)
            cb[q] = relu_(fmaf(s0, wv2[q], fmaf(s1, wv2[4 + q], bv2[q])));
        float r0 = relu_(fmaf(xpb, wp1[0], bp1[0]));
        float r1 = relu_(fmaf(xpb, wp1[1], bp1[1]));
#pragma unroll
        for (int q = 0; q < 4; q++)
            cb[4 + q] = relu_(fmaf(r0, wp2[q], fmaf(r1, wp2[4 + q], bp2[q])));
    }

    // ---- pd row i, k-outer (R10 pattern): live ca+cb+pd = 32 ----
    float pd[16];
#pragma unroll
    for (int k = 0; k < 16; k++) {
        float da = be[k], db = be[k];
#pragma unroll
        for (int f = 0; f < 8; f++) {
            const float wf = we[f * 16 + k];          // uniform -> s_load
            da = fmaf(ca[f], wf, da);
            db = fmaf(cb[f], wf, db);
        }
        pd[k] = relu_(da) + relu_(db);
    }

    // ---- stage 3: jh=0 -> u row i (+bc1), jh=1 -> v row i; both to LDS.
    // Two 10-col half-passes, acc = 5 f32x2 (10 regs live).
    const int myrow = ((w * 4 + g) * 16 + jh * 8 + i) * 20;
    const int wrow  = jh * 16;                        // wc1 rows 0-15 / 16-31
#pragma unroll
    for (int half = 0; half < 2; half++) {
        f32x2 acc[5];
#pragma unroll
        for (int c = 0; c < 5; c++) {
            if (jh == 0) acc[c] = *(const f32x2*)&bc1[half * 10 + 2 * c];
            else { acc[c].x = 0.f; acc[c].y = 0.f; }
        }
#pragma unroll
        for (int k = 0; k < 16; k++) {
            f32x2 pv; pv.x = pd[k]; pv.y = pd[k];
#pragma unroll
            for (int c = 0; c < 5; c++)
                pk_fma_sw(acc[c], pv,
                          *(const f32x2*)&wc1[(wrow + k) * 20 + half * 10 + 2 * c]);
        }
#pragma unroll
        for (int c = 0; c < 5; c++)
            *(f32x2*)&s_uv[myrow + half * 10 + 2 * c] = acc[c];  // ds_write_b64
    }
    wave_sync();   // per-wave LDS region; wave lockstep => visible to all lanes

    // ---- stage 4: lane owns (i, jh); four iterations, one j each ----
    const float c0 = ykg[1536];                       // uniform -> s_load
    const int gbase = (w * 4 + g) * 16 * 20;
    const float* __restrict__ ykrow = ykg + i * 192;  // + j*24 + half*12

#pragma unroll 1
    for (int t = 0; t < 4; t++) {
        const int j = jh * 4 + t;

        // h1 = relu(u[i] + v[j]) : 10x ds_read_b128 (broadcast groups)
        float h1[20];
#pragma unroll
        for (int p = 0; p < 5; p++) {
            f32x4 uq = *(const f32x4*)&s_uv[gbase + i * 20 + 4 * p];
            f32x4 vq = *(const f32x4*)&s_uv[gbase + (8 + j) * 20 + 4 * p];
            h1[4*p+0] = relu_(uq.x + vq.x);
            h1[4*p+1] = relu_(uq.y + vq.y);
            h1[4*p+2] = relu_(uq.z + vq.z);
            h1[4*p+3] = relu_(uq.w + vq.w);
        }

        float z = 0.f;
#pragma unroll
        for (int half = 0; half < 2; half++) {
            f32x2 sA[5];
#pragma unroll
            for (int c = 0; c < 5; c++)
                sA[c] = *(const f32x2*)&bc2[half * 10 + 2 * c];
#pragma unroll
            for (int k = 0; k < 20; k++) {
                f32x2 hv; hv.x = h1[k]; hv.y = h1[k];
#pragma unroll
                for (int c = 0; c < 5; c++)
                    pk_fma_sw(sA[c], hv,
                              *(const f32x2*)&wc2[k * 20 + half * 10 + 2 * c]);
            }
            // yk half: 2x b128 + 1x b64 (12-padded halves, aligned)
            const float* yh = ykrow + j * 24 + half * 12;
            f32x4 y0 = *(const f32x4*)&yh[0];
            f32x4 y1 = *(const f32x4*)&yh[4];
            f32x2 y2 = *(const f32x2*)&yh[8];
            z = fmaf(relu_(sA[0].x), y0.x, z);
            z = fmaf(relu_(sA[0].y), y0.y, z);
            z = fmaf(relu_(sA[1].x), y0.z, z);
            z = fmaf(relu_(sA[1].y), y0.w, z);
            z = fmaf(relu_(sA[2].x), y1.x, z);
            z = fmaf(relu_(sA[2].y), y1.y, z);
            z = fmaf(relu_(sA[3].x), y1.z, z);
            z = fmaf(relu_(sA[3].y), y1.w, z);
            z = fmaf(relu_(sA[4].x), y2.x, z);
            z = fmaf(relu_(sA[4].y), y2.y, z);
        }
        if (b < Btot)
            out[b * 64 + i * 8 + j] = c0 + z;
    }
}

extern "C" void kernel_launch(void* const* d_in, const int* in_sizes, int n_in,
                              void* d_out, int out_size, void* d_ws, size_t ws_size,
                              hipStream_t stream) {
    const float* x    = (const float*)d_in[0];
    const float* mask = (const float*)d_in[1];
    const float* wv1  = (const float*)d_in[2];
    const float* bv1  = (const float*)d_in[3];
    const float* wv2  = (const float*)d_in[4];
    const float* bv2  = (const float*)d_in[5];
    const float* wp1  = (const float*)d_in[6];
    const float* bp1  = (const float*)d_in[7];
    const float* wp2  = (const float*)d_in[8];
    const float* bp2  = (const float*)d_in[9];
    const float* we   = (const float*)d_in[10];
    const float* be   = (const float*)d_in[11];
    const float* wc1  = (const float*)d_in[12];
    const float* bc1  = (const float*)d_in[13];
    const float* wc2  = (const float*)d_in[14];
    const float* bc2  = (const float*)d_in[15];
    const float* wm1  = (const float*)d_in[16];
    const float* bm1  = (const float*)d_in[17];
    const float* wm2  = (const float*)d_in[18];
    const float* bm2  = (const float*)d_in[19];
    const float* wm3  = (const float*)d_in[20];
    const float* bm3  = (const float*)d_in[21];
    const float* wk1  = (const float*)d_in[22];
    const float* bk1  = (const float*)d_in[23];
    const float* wk2  = (const float*)d_in[24];
    const float* bk2  = (const float*)d_in[25];
    float* out = (float*)d_out;
    float* ws  = (float*)d_ws;

    int Btot = in_sizes[0] / 16;                 // 32768

    yk_kernel<<<1, 256, 0, stream>>>(mask, wm1, bm1, wm2, bm2, wm3, bm3,
                                     wk1, bk1, wk2, bk2, ws);

    int grid = (Btot + 15) / 16;                 // 16 batches per 256-thr block
    frap_kernel<<<grid, 256, 0, stream>>>(
        x, wv1, bv1, wv2, bv2, wp1, bp1, wp2, bp2, we, be,
        wc1, bc1, wc2, bc2, ws, out, Btot);
}